// Round 1
// baseline (2186.604 us; speedup 1.0000x reference)
//
#include <hip/hip_runtime.h>
#include <stdint.h>

#define TSTEPS 1000
#define NB 256
#define NF 64
#define NH 256   // H1 == H2 == 256

// Prep: transpose W2 (H2,H1) -> W2T[h1][h2] in d_ws for coalesced gathers,
// and zero the two global spike counters.
__global__ void snn_prep(const float* __restrict__ W2, float* __restrict__ W2T,
                         unsigned int* __restrict__ counts) {
    int idx = blockIdx.x * 256 + threadIdx.x;     // idx = h1*256 + h2
    W2T[idx] = W2[(idx & 255) * 256 + (idx >> 8)];
    if (idx < 2) counts[idx] = 0u;
}

// Main: one workgroup per batch, thread h = hidden unit (h1 for layer1 state,
// h2 for layer2 state). 1000 sequential steps, sparse gather both layers.
__launch_bounds__(256, 1)
__global__ void snn_main(const float* __restrict__ spikes,
                         const float* __restrict__ W1,
                         const float* __restrict__ b1,
                         const float* __restrict__ W2T,
                         const float* __restrict__ b2,
                         const float* __restrict__ Wr,
                         const float* __restrict__ br,
                         float* __restrict__ out,
                         unsigned int* __restrict__ counts) {
    const int b = blockIdx.x;
    const int h = threadIdx.x;
    const int lane = h & 63;
    const int wv = h >> 6;

    __shared__ float W1T[NF][NH + 1];       // +1 pad: conflict-free both ways
    __shared__ float xbuf[16 * NF];         // 16-step input chunk
    __shared__ unsigned char slist[2][256]; // per-wave compacted spk1 lists
    __shared__ int scnt[2][4];
    __shared__ float rp0[4], rp1[4];
    __shared__ int rc1[4], rc2[4];

    // stage W1 transposed: W1T[f][h1] = W1[h1*64+f]; coalesced global reads.
    // Visibility guaranteed by the t=0 xbuf staging __syncthreads below.
    for (int i = h; i < NH * NF; i += 256) {
        W1T[i & 63][i >> 6] = W1[i];
    }

    const float b1h = b1[h];
    const float b2h = b2[h];
    float mem1 = 0.f, mem2 = 0.f, mem2s = 0.f;
    int cnt1 = 0, cnt2 = 0;

    for (int t = 0; t < TSTEPS; ++t) {
        if ((t & 15) == 0) {
            // stage next 16 input rows (16x64 floats), coalesced per wave
            #pragma unroll
            for (int k = 0; k < 4; ++k) {
                int idx = k * 256 + h;
                int tt = idx >> 6, f = idx & 63;
                int tg = t + tt;
                xbuf[idx] = (tg < TSTEPS)
                    ? spikes[(size_t)tg * (NB * NF) + b * NF + f] : 0.f;
            }
            __syncthreads();   // also covers W1T staging at t==0
        }
        // input mask: every wave computes it redundantly -> wave-uniform SGPR
        float xv = xbuf[((t & 15) << 6) | lane];
        unsigned long long xmask = __ballot(xv > 0.f);

        // layer 1: sparse gather from LDS, 4 independent chains for ILP
        unsigned xm0 = (unsigned)(xmask & 0xFFFFull);
        unsigned xm1 = (unsigned)((xmask >> 16) & 0xFFFFull);
        unsigned xm2 = (unsigned)((xmask >> 32) & 0xFFFFull);
        unsigned xm3 = (unsigned)((xmask >> 48) & 0xFFFFull);
        float a0 = 0.f, a1 = 0.f, a2 = 0.f, a3 = 0.f;
        while (xm0 | xm1 | xm2 | xm3) {
            if (xm0) { int f = __builtin_ctz(xm0); xm0 &= xm0 - 1; a0 += W1T[f][h]; }
            if (xm1) { int f = __builtin_ctz(xm1); xm1 &= xm1 - 1; a1 += W1T[f + 16][h]; }
            if (xm2) { int f = __builtin_ctz(xm2); xm2 &= xm2 - 1; a2 += W1T[f + 32][h]; }
            if (xm3) { int f = __builtin_ctz(xm3); xm3 &= xm3 - 1; a3 += W1T[f + 48][h]; }
        }
        float cur1 = b1h + ((a0 + a1) + (a2 + a3));

        float reset1 = (mem1 > 1.f) ? 1.f : 0.f;
        mem1 = 0.8187307530779818f * mem1 + cur1 - reset1;   // beta1 = exp(-1/5)
        bool s1 = (mem1 - 1.f) > 0.f;
        cnt1 += (int)s1;

        // publish spk1 as compacted per-wave index lists (double-buffered)
        unsigned long long smask = __ballot(s1);
        int buf = t & 1;
        if (lane == 0) scnt[buf][wv] = __popcll(smask);
        if (s1) {
            int rank = __popcll(smask & ((1ull << lane) - 1ull));
            slist[buf][(wv << 6) + rank] = (unsigned char)h;
        }
        __syncthreads();   // single barrier per step

        // layer 2: sparse gather of W2T rows from L1/L2, 4 lockstep chains
        int c0 = scnt[buf][0], c1 = scnt[buf][1];
        int c2 = scnt[buf][2], c3 = scnt[buf][3];
        int nmax = max(max(c0, c1), max(c2, c3));
        float q0 = 0.f, q1 = 0.f, q2 = 0.f, q3 = 0.f;
        const float* W2Th = W2T + h;
        const unsigned char* sl = slist[buf];
        for (int i = 0; i < nmax; ++i) {
            if (i < c0) q0 += W2Th[(int)sl[i] << 8];
            if (i < c1) q1 += W2Th[(int)sl[64 + i] << 8];
            if (i < c2) q2 += W2Th[(int)sl[128 + i] << 8];
            if (i < c3) q3 += W2Th[(int)sl[192 + i] << 8];
        }
        float cur2 = b2h + ((q0 + q1) + (q2 + q3));

        float reset2 = (mem2 > 1.f) ? 1.f : 0.f;
        mem2 = 0.9048374180359595f * mem2 + cur2 - reset2;   // beta2 = exp(-1/10)
        bool s2 = (mem2 - 1.f) > 0.f;
        cnt2 += (int)s2;
        mem2s += mem2;
    }

    // readout: out[b,:] = (mem2_sum/T) @ Wr.T + br ; block-level reduction
    float v = mem2s / 1000.0f;
    float p0 = v * Wr[h];
    float p1 = v * Wr[NH + h];
    int rcs1 = cnt1, rcs2 = cnt2;
    for (int off = 32; off > 0; off >>= 1) {
        p0 += __shfl_down(p0, off);
        p1 += __shfl_down(p1, off);
        rcs1 += __shfl_down(rcs1, off);
        rcs2 += __shfl_down(rcs2, off);
    }
    if (lane == 0) { rp0[wv] = p0; rp1[wv] = p1; rc1[wv] = rcs1; rc2[wv] = rcs2; }
    __syncthreads();
    if (h == 0) {
        out[2 * b]     = ((rp0[0] + rp0[1]) + (rp0[2] + rp0[3])) + br[0];
        out[2 * b + 1] = ((rp1[0] + rp1[1]) + (rp1[2] + rp1[3])) + br[1];
        atomicAdd(&counts[0], (unsigned)(rc1[0] + rc1[1] + rc1[2] + rc1[3]));
        atomicAdd(&counts[1], (unsigned)(rc2[0] + rc2[1] + rc2[2] + rc2[3]));
    }
}

__global__ void snn_finalize(const unsigned int* __restrict__ counts,
                             float* __restrict__ out) {
    if (threadIdx.x < 2)
        out[512 + threadIdx.x] = (float)counts[threadIdx.x] / 65536000.0f; // T*B*256
}

extern "C" void kernel_launch(void* const* d_in, const int* in_sizes, int n_in,
                              void* d_out, int out_size, void* d_ws, size_t ws_size,
                              hipStream_t stream) {
    const float* spikes = (const float*)d_in[0];
    const float* W1     = (const float*)d_in[1];
    const float* b1     = (const float*)d_in[2];
    const float* W2     = (const float*)d_in[3];
    const float* b2     = (const float*)d_in[4];
    const float* Wr     = (const float*)d_in[5];
    const float* br     = (const float*)d_in[6];
    float* out = (float*)d_out;

    float* W2T = (float*)d_ws;                                   // 256 KB
    unsigned int* counts = (unsigned int*)((char*)d_ws + (size_t)NH * NH * sizeof(float));

    snn_prep<<<256, 256, 0, stream>>>(W2, W2T, counts);
    snn_main<<<256, 256, 0, stream>>>(spikes, W1, b1, W2T, b2, Wr, br, out, counts);
    snn_finalize<<<1, 64, 0, stream>>>(counts, out);
}